// Round 3
// baseline (743.934 us; speedup 1.0000x reference)
//
#include <hip/hip_runtime.h>
#include <math.h>

// Problem constants (match reference)
constexpr int NR = 3200;
constexpr int NA = 320;
constexpr int TD = 512;
constexpr int DD = 128;
constexpr int H  = 128;
constexpr int B  = 8;

constexpr int ROWS_T  = 4;
constexpr int ROWS_D  = 8;
constexpr int NBLK_T  = NR / ROWS_T;   // 800
constexpr int NBLK_D  = NA / ROWS_D;   // 40
constexpr int NBLK_MM = NR;            // 3200

typedef float f4 __attribute__((ext_vector_type(4)));

// cells[0..B)   = min bits (init +inf)
// cells[B..2B)  = max bits (init -inf)
__global__ void init_minmax(int* cells) {
    const int t = threadIdx.x;
    if (t < B) {
        cells[t]     = 0x7F800000;       // +inf
        cells[B + t] = (int)0xFF800000;  // -inf
    }
}

// ---------------- mega: gemm_t | gemm_d | per-residue min/max -----------
__global__ __launch_bounds__(256) void mega_kernel(
    const float* __restrict__ At, const float* __restrict__ Wt, const float* __restrict__ bt,
    const float* __restrict__ Ad, const float* __restrict__ Wd, const float* __restrict__ bd,
    const float* __restrict__ tpos, const float* __restrict__ dpos,
    const int* __restrict__ seg_res, const int* __restrict__ seg_atom,
    float* __restrict__ tf, float* __restrict__ df, int* __restrict__ cells) {
    __shared__ float sA[ROWS_T * TD];   // 8 KB (also fits ROWS_D*DD = 1024)
    __shared__ float sAcc[ROWS_D * H];  // 4 KB (also used by minmax reduce)
    const int b = blockIdx.x;
    const int t = threadIdx.x;

    if (b < NBLK_T) {
        // ---- target GEMM: out[N,H] = A[N,512] @ W + b, k-split halves ----
        const int h = t & (H - 1), half = t >> 7, i0 = b * ROWS_T;
        for (int idx = t; idx < ROWS_T * TD; idx += 256)
            sA[idx] = At[i0 * TD + idx];
        __syncthreads();
        float acc[ROWS_T];
#pragma unroll
        for (int r = 0; r < ROWS_T; r++) acc[r] = 0.0f;
        const int k0 = half * (TD / 2), k1 = k0 + (TD / 2);
#pragma unroll 4
        for (int k = k0; k < k1; k++) {
            const float w = Wt[k * H + h];
#pragma unroll
            for (int r = 0; r < ROWS_T; r++)
                acc[r] = fmaf(sA[r * TD + k], w, acc[r]);
        }
        if (half) {
#pragma unroll
            for (int r = 0; r < ROWS_T; r++) sAcc[r * H + h] = acc[r];
        }
        __syncthreads();
        if (!half) {
            const float bv = bt[h];
#pragma unroll
            for (int r = 0; r < ROWS_T; r++)
                tf[(i0 + r) * H + h] = acc[r] + sAcc[r * H + h] + bv;
        }
    } else if (b < NBLK_T + NBLK_D) {
        // ---- drug GEMM: K=128, ROWS_D=8, k-split halves ----
        const int h = t & (H - 1), half = t >> 7, i0 = (b - NBLK_T) * ROWS_D;
        for (int idx = t; idx < ROWS_D * DD; idx += 256)
            sA[idx] = Ad[i0 * DD + idx];
        __syncthreads();
        float acc[ROWS_D];
#pragma unroll
        for (int r = 0; r < ROWS_D; r++) acc[r] = 0.0f;
        const int k0 = half * (DD / 2), k1 = k0 + (DD / 2);
#pragma unroll 4
        for (int k = k0; k < k1; k++) {
            const float w = Wd[k * H + h];
#pragma unroll
            for (int r = 0; r < ROWS_D; r++)
                acc[r] = fmaf(sA[r * DD + k], w, acc[r]);
        }
        if (half) {
#pragma unroll
            for (int r = 0; r < ROWS_D; r++) sAcc[r * H + h] = acc[r];
        }
        __syncthreads();
        if (!half) {
            const float bv = bd[h];
#pragma unroll
            for (int r = 0; r < ROWS_D; r++)
                df[(i0 + r) * H + h] = acc[r] + sAcc[r * H + h] + bv;
        }
    } else {
        // ---- per-residue masked min/max over atoms ----
        const int i  = b - NBLK_T - NBLK_D;
        const int sr = seg_res[i];
        const float tx = tpos[3 * i], ty = tpos[3 * i + 1], tz = tpos[3 * i + 2];
        float vmin = INFINITY, vmax = -INFINITY;
        for (int j = t; j < NA; j += 256) {
            if (seg_atom[j] == sr) {
                const float dx = tx - dpos[3 * j];
                const float dy = ty - dpos[3 * j + 1];
                const float dz = tz - dpos[3 * j + 2];
                const float d  = sqrtf(dx * dx + dy * dy + dz * dz);
                vmin = fminf(vmin, d);
                vmax = fmaxf(vmax, d);
            }
        }
#pragma unroll
        for (int off = 32; off > 0; off >>= 1) {
            vmin = fminf(vmin, __shfl_down(vmin, off));
            vmax = fmaxf(vmax, __shfl_down(vmax, off));
        }
        const int wid = t >> 6, lane = t & 63;
        if (lane == 0) { sAcc[wid] = vmin; sAcc[4 + wid] = vmax; }
        __syncthreads();
        if (t == 0) {
            float mn = sAcc[0], mx = sAcc[4];
#pragma unroll
            for (int w = 1; w < 4; w++) {
                mn = fminf(mn, sAcc[w]);
                mx = fmaxf(mx, sAcc[4 + w]);
            }
            // distances >= 0 -> float order == signed-int bit order
            if (mn < INFINITY)  atomicMin(&cells[sr],     __float_as_int(mn));
            if (mx > -INFINITY) atomicMax(&cells[B + sr], __float_as_int(mx));
        }
    }
}

// ---------------- fast tanh --------------------------------------------
__device__ __forceinline__ float fast_tanh(float x) {
    const float cx = fminf(fmaxf(x, -15.0f), 15.0f);
    const float e  = __expf(2.0f * cx);
    return 1.0f - __fdividef(2.0f, e + 1.0f);
}

// ---------------- the 524 MB writer -------------------------------------
// grid = (20, NR): blockIdx.y = residue i (no integer division anywhere),
// thread -> 8 consecutive h elements (2x nontemporal float4). Distance is
// recomputed from positions (L1/L2-resident); segment params decoded inline
// from the atomic cells.
__global__ __launch_bounds__(256) void final_kernel(
    const float* __restrict__ tf, const float* __restrict__ df,
    const float* __restrict__ tpos, const float* __restrict__ dpos,
    const int* __restrict__ seg_res, const int* __restrict__ seg_atom,
    const int* __restrict__ cells, float* __restrict__ out) {
    const int i = blockIdx.y;
    const int e = (blockIdx.x * 256 + threadIdx.x) * 8;  // elem within row i
    const int j = e >> 7;
    const int h = e & 127;

    f4 o0 = {0.0f, 0.0f, 0.0f, 0.0f};
    f4 o1 = {0.0f, 0.0f, 0.0f, 0.0f};
    const int sr = seg_res[i];
    if (seg_atom[j] == sr) {
        const int mnb = cells[sr];
        const int mxb = cells[B + sr];
        const float dmin = (mnb == 0x7F800000) ? 0.0f : __int_as_float(mnb);
        const float dmax = (mxb == (int)0xFF800000) ? 1.0f : __int_as_float(mxb);
        const float inv  = 1.0f / ((dmax > dmin) ? (dmax - dmin) : 1.0f);
        const float dx = tpos[3 * i]     - dpos[3 * j];
        const float dy = tpos[3 * i + 1] - dpos[3 * j + 1];
        const float dz = tpos[3 * i + 2] - dpos[3 * j + 2];
        const float dn = (sqrtf(dx * dx + dy * dy + dz * dz) - dmin) * inv;
        const f4 tv0 = *(const f4*)(tf + i * H + h);
        const f4 tv1 = *(const f4*)(tf + i * H + h + 4);
        const f4 dv0 = *(const f4*)(df + j * H + h);
        const f4 dv1 = *(const f4*)(df + j * H + h + 4);
        o0.x = fast_tanh(tv0.x - dv0.x + dn);
        o0.y = fast_tanh(tv0.y - dv0.y + dn);
        o0.z = fast_tanh(tv0.z - dv0.z + dn);
        o0.w = fast_tanh(tv0.w - dv0.w + dn);
        o1.x = fast_tanh(tv1.x - dv1.x + dn);
        o1.y = fast_tanh(tv1.y - dv1.y + dn);
        o1.z = fast_tanh(tv1.z - dv1.z + dn);
        o1.w = fast_tanh(tv1.w - dv1.w + dn);
    }
    float* dst = out + (long long)i * (NA * H) + e;
    __builtin_nontemporal_store(o0, (f4*)dst);
    __builtin_nontemporal_store(o1, (f4*)(dst + 4));
}

extern "C" void kernel_launch(void* const* d_in, const int* in_sizes, int n_in,
                              void* d_out, int out_size, void* d_ws, size_t ws_size,
                              hipStream_t stream) {
    const float* target_feature = (const float*)d_in[0];  // [NR, TD]
    const float* drug_feature   = (const float*)d_in[1];  // [NA, DD]
    const float* target_pos     = (const float*)d_in[2];  // [NR, 3]
    const float* drug_pos       = (const float*)d_in[3];  // [NA, 3]
    const float* Wt             = (const float*)d_in[4];  // [TD, H]
    const float* bt             = (const float*)d_in[5];  // [H]
    const float* Wd             = (const float*)d_in[6];  // [DD, H]
    const float* bd             = (const float*)d_in[7];  // [H]
    const int*   seg_res        = (const int*)d_in[8];    // [NR]
    const int*   seg_atom       = (const int*)d_in[9];    // [NA]
    float* out = (float*)d_out;

    // workspace layout (floats): tf | df | cells(2B ints)
    float* ws = (float*)d_ws;
    float* tf = ws;                 // NR*H = 409,600
    float* df = tf + NR * H;        // NA*H =  40,960
    int*   cells = (int*)(df + NA * H);  // 2*B ints

    init_minmax<<<1, 64, 0, stream>>>(cells);
    mega_kernel<<<NBLK_T + NBLK_D + NBLK_MM, 256, 0, stream>>>(
        target_feature, Wt, bt, drug_feature, Wd, bd,
        target_pos, drug_pos, seg_res, seg_atom, tf, df, cells);
    final_kernel<<<dim3(NA * H / (8 * 256), NR), 256, 0, stream>>>(
        tf, df, target_pos, drug_pos, seg_res, seg_atom, cells, out);
}

// Round 4
// 566.699 us; speedup vs baseline: 1.3128x; 1.3128x over previous
//
#include <hip/hip_runtime.h>
#include <math.h>

// Problem constants (match reference)
constexpr int NR = 3200;
constexpr int NA = 320;
constexpr int TD = 512;
constexpr int DD = 128;
constexpr int H  = 128;
constexpr int B  = 8;
constexpr int NP = NR * NA;                     // 1,024,000 pairs
constexpr long long TOTAL = (long long)NP * H;  // 131,072,000 output elems

constexpr int ROWS_T = 4;
constexpr int ROWS_D = 8;
constexpr int NBLK_T = NR / ROWS_T;   // 800
constexpr int NBLK_D = NA / ROWS_D;   // 40

typedef float f4 __attribute__((ext_vector_type(4)));

// ---------------- mega: gemm_t | gemm_d | per-residue dist/min/max ------
// No atomics anywhere: dist blocks write rowmin/rowmax densely.
__global__ __launch_bounds__(256) void mega_kernel(
    const float* __restrict__ At, const float* __restrict__ Wt, const float* __restrict__ bt,
    const float* __restrict__ Ad, const float* __restrict__ Wd, const float* __restrict__ bd,
    const float* __restrict__ tpos, const float* __restrict__ dpos,
    const int* __restrict__ seg_res, const int* __restrict__ seg_atom,
    float* __restrict__ tf, float* __restrict__ df,
    float* __restrict__ Dbuf, float* __restrict__ rowmin, float* __restrict__ rowmax) {
    __shared__ float sA[ROWS_T * TD];   // 8 KB (fits ROWS_D*DD = 1024 too)
    __shared__ float sAcc[ROWS_D * H];  // 4 KB (also the minmax reduce scratch)
    const int b = blockIdx.x;
    const int t = threadIdx.x;

    if (b < NBLK_T) {
        // ---- target GEMM: k-split halves across 256 threads ----
        const int h = t & (H - 1), half = t >> 7, i0 = b * ROWS_T;
        for (int idx = t; idx < ROWS_T * TD; idx += 256)
            sA[idx] = At[i0 * TD + idx];
        __syncthreads();
        float acc[ROWS_T];
#pragma unroll
        for (int r = 0; r < ROWS_T; r++) acc[r] = 0.0f;
        const int k0 = half * (TD / 2), k1 = k0 + (TD / 2);
#pragma unroll 4
        for (int k = k0; k < k1; k++) {
            const float w = Wt[k * H + h];
#pragma unroll
            for (int r = 0; r < ROWS_T; r++)
                acc[r] = fmaf(sA[r * TD + k], w, acc[r]);
        }
        if (half) {
#pragma unroll
            for (int r = 0; r < ROWS_T; r++) sAcc[r * H + h] = acc[r];
        }
        __syncthreads();
        if (!half) {
            const float bv = bt[h];
#pragma unroll
            for (int r = 0; r < ROWS_T; r++)
                tf[(i0 + r) * H + h] = acc[r] + sAcc[r * H + h] + bv;
        }
    } else if (b < NBLK_T + NBLK_D) {
        // ---- drug GEMM ----
        const int h = t & (H - 1), half = t >> 7, i0 = (b - NBLK_T) * ROWS_D;
        for (int idx = t; idx < ROWS_D * DD; idx += 256)
            sA[idx] = Ad[i0 * DD + idx];
        __syncthreads();
        float acc[ROWS_D];
#pragma unroll
        for (int r = 0; r < ROWS_D; r++) acc[r] = 0.0f;
        const int k0 = half * (DD / 2), k1 = k0 + (DD / 2);
#pragma unroll 4
        for (int k = k0; k < k1; k++) {
            const float w = Wd[k * H + h];
#pragma unroll
            for (int r = 0; r < ROWS_D; r++)
                acc[r] = fmaf(sA[r * DD + k], w, acc[r]);
        }
        if (half) {
#pragma unroll
            for (int r = 0; r < ROWS_D; r++) sAcc[r * H + h] = acc[r];
        }
        __syncthreads();
        if (!half) {
            const float bv = bd[h];
#pragma unroll
            for (int r = 0; r < ROWS_D; r++)
                df[(i0 + r) * H + h] = acc[r] + sAcc[r * H + h] + bv;
        }
    } else {
        // ---- per-residue distances + masked row min/max (dense write) ----
        const int i  = b - NBLK_T - NBLK_D;
        const int sr = seg_res[i];
        const float tx = tpos[3 * i], ty = tpos[3 * i + 1], tz = tpos[3 * i + 2];
        float vmin = INFINITY, vmax = -INFINITY;
        for (int j = t; j < NA; j += 256) {
            const float dx = tx - dpos[3 * j];
            const float dy = ty - dpos[3 * j + 1];
            const float dz = tz - dpos[3 * j + 2];
            const float d  = sqrtf(dx * dx + dy * dy + dz * dz);
            Dbuf[i * NA + j] = d;
            if (seg_atom[j] == sr) {
                vmin = fminf(vmin, d);
                vmax = fmaxf(vmax, d);
            }
        }
#pragma unroll
        for (int off = 32; off > 0; off >>= 1) {
            vmin = fminf(vmin, __shfl_down(vmin, off));
            vmax = fmaxf(vmax, __shfl_down(vmax, off));
        }
        const int wid = t >> 6, lane = t & 63;
        if (lane == 0) { sAcc[wid] = vmin; sAcc[4 + wid] = vmax; }
        __syncthreads();
        if (t == 0) {
            float mn = sAcc[0], mx = sAcc[4];
#pragma unroll
            for (int w = 1; w < 4; w++) {
                mn = fminf(mn, sAcc[w]);
                mx = fmaxf(mx, sAcc[4 + w]);
            }
            rowmin[i] = mn;
            rowmax[i] = mx;
        }
    }
}

// ---------------- segment reduce -> params[B] = {dmin, 1/denom} ---------
// 1 block, 512 threads, wave s handles segment s. No atomics.
__global__ __launch_bounds__(512) void segreduce_kernel(
    const float* __restrict__ rowmin, const float* __restrict__ rowmax,
    const int* __restrict__ seg_res, float2* __restrict__ params) {
    const int s    = threadIdx.x >> 6;  // 0..7
    const int lane = threadIdx.x & 63;
    float mn = INFINITY, mx = -INFINITY;
    for (int r = lane; r < NR; r += 64) {
        if (seg_res[r] == s) {
            mn = fminf(mn, rowmin[r]);
            mx = fmaxf(mx, rowmax[r]);
        }
    }
#pragma unroll
    for (int off = 32; off > 0; off >>= 1) {
        mn = fminf(mn, __shfl_down(mn, off));
        mx = fmaxf(mx, __shfl_down(mx, off));
    }
    if (lane == 0) {
        const float dmin = (mn < INFINITY)  ? mn : 0.0f;
        const float dmax = (mx > -INFINITY) ? mx : 1.0f;
        const float denom = (dmax > dmin) ? (dmax - dmin) : 1.0f;
        params[s] = make_float2(dmin, 1.0f / denom);
    }
}

// ---------------- fast tanh --------------------------------------------
__device__ __forceinline__ float fast_tanh(float x) {
    const float cx = fminf(fmaxf(x, -15.0f), 15.0f);
    const float e  = __expf(2.0f * cx);
    return 1.0f - __fdividef(2.0f, e + 1.0f);
}

// ---------------- the 524 MB writer -------------------------------------
// Round-2 shape (known good): 1D grid, 4 contiguous elems/thread, NT f4
// stores (1 KB/wave-instruction, fully coalesced). The 32 lanes sharing a
// pair broadcast-load Dbuf[p]/seg/params.
__global__ __launch_bounds__(256) void final_kernel(
    const float* __restrict__ tf, const float* __restrict__ df,
    const float* __restrict__ Dbuf,
    const int* __restrict__ seg_res, const int* __restrict__ seg_atom,
    const float2* __restrict__ params, float* __restrict__ out) {
    const int t    = blockIdx.x * 256 + threadIdx.x;  // < 32,768,000
    const int base = t << 2;                          // elem idx < 131,072,000
    const int p    = base >> 7;                       // pair index
    const int h    = base & 127;                      // h offset
    const int i    = p / NA;
    const int j    = p - i * NA;

    f4 o = {0.0f, 0.0f, 0.0f, 0.0f};
    const int sr = seg_res[i];
    if (sr == seg_atom[j]) {
        const float2 pp = params[sr];
        const float  dn = (Dbuf[p] - pp.x) * pp.y;
        const f4 tv = *(const f4*)(tf + i * H + h);
        const f4 dv = *(const f4*)(df + j * H + h);
        o.x = fast_tanh(tv.x - dv.x + dn);
        o.y = fast_tanh(tv.y - dv.y + dn);
        o.z = fast_tanh(tv.z - dv.z + dn);
        o.w = fast_tanh(tv.w - dv.w + dn);
    }
    __builtin_nontemporal_store(o, (f4*)(out + base));
}

extern "C" void kernel_launch(void* const* d_in, const int* in_sizes, int n_in,
                              void* d_out, int out_size, void* d_ws, size_t ws_size,
                              hipStream_t stream) {
    const float* target_feature = (const float*)d_in[0];  // [NR, TD]
    const float* drug_feature   = (const float*)d_in[1];  // [NA, DD]
    const float* target_pos     = (const float*)d_in[2];  // [NR, 3]
    const float* drug_pos       = (const float*)d_in[3];  // [NA, 3]
    const float* Wt             = (const float*)d_in[4];  // [TD, H]
    const float* bt             = (const float*)d_in[5];  // [H]
    const float* Wd             = (const float*)d_in[6];  // [DD, H]
    const float* bd             = (const float*)d_in[7];  // [H]
    const int*   seg_res        = (const int*)d_in[8];    // [NR]
    const int*   seg_atom       = (const int*)d_in[9];    // [NA]
    float* out = (float*)d_out;

    // workspace (floats): tf | df | Dbuf | rowmin | rowmax | params
    float* ws     = (float*)d_ws;
    float* tf     = ws;                  // NR*H = 409,600
    float* df     = tf + NR * H;         // NA*H =  40,960
    float* Dbuf   = df + NA * H;         // NP   = 1,024,000
    float* rowmin = Dbuf + NP;           // NR
    float* rowmax = rowmin + NR;         // NR
    float2* params = (float2*)(rowmax + NR);  // B

    mega_kernel<<<NBLK_T + NBLK_D + NR, 256, 0, stream>>>(
        target_feature, Wt, bt, drug_feature, Wd, bd,
        target_pos, drug_pos, seg_res, seg_atom, tf, df, Dbuf, rowmin, rowmax);
    segreduce_kernel<<<1, 512, 0, stream>>>(rowmin, rowmax, seg_res, params);
    final_kernel<<<(int)(TOTAL / 4 / 256), 256, 0, stream>>>(
        tf, df, Dbuf, seg_res, seg_atom, params, out);
}

// Round 5
// 563.066 us; speedup vs baseline: 1.3212x; 1.0065x over previous
//
#include <hip/hip_runtime.h>
#include <math.h>

// Problem constants (match reference)
constexpr int NR = 3200;
constexpr int NA = 320;
constexpr int TD = 512;
constexpr int DD = 128;
constexpr int H  = 128;
constexpr int B  = 8;
constexpr int NP = NR * NA;                     // 1,024,000 pairs

constexpr int ROWS_T = 4;
constexpr int ROWS_D = 8;
constexpr int NBLK_T = NR / ROWS_T;   // 800
constexpr int NBLK_D = NA / ROWS_D;   // 40

typedef float f4 __attribute__((ext_vector_type(4)));

// ---------------- mega: gemm_t | gemm_d | per-residue dist/min/max ------
// No atomics anywhere: dist blocks write rowmin/rowmax densely.
__global__ __launch_bounds__(256) void mega_kernel(
    const float* __restrict__ At, const float* __restrict__ Wt, const float* __restrict__ bt,
    const float* __restrict__ Ad, const float* __restrict__ Wd, const float* __restrict__ bd,
    const float* __restrict__ tpos, const float* __restrict__ dpos,
    const int* __restrict__ seg_res, const int* __restrict__ seg_atom,
    float* __restrict__ tf, float* __restrict__ df,
    float* __restrict__ Dbuf, float* __restrict__ rowmin, float* __restrict__ rowmax) {
    __shared__ float sA[ROWS_T * TD];   // 8 KB (fits ROWS_D*DD = 1024 too)
    __shared__ float sAcc[ROWS_D * H];  // 4 KB (also the minmax reduce scratch)
    const int b = blockIdx.x;
    const int t = threadIdx.x;

    if (b < NBLK_T) {
        // ---- target GEMM: k-split halves across 256 threads ----
        const int h = t & (H - 1), half = t >> 7, i0 = b * ROWS_T;
        for (int idx = t; idx < ROWS_T * TD; idx += 256)
            sA[idx] = At[i0 * TD + idx];
        __syncthreads();
        float acc[ROWS_T];
#pragma unroll
        for (int r = 0; r < ROWS_T; r++) acc[r] = 0.0f;
        const int k0 = half * (TD / 2), k1 = k0 + (TD / 2);
#pragma unroll 4
        for (int k = k0; k < k1; k++) {
            const float w = Wt[k * H + h];
#pragma unroll
            for (int r = 0; r < ROWS_T; r++)
                acc[r] = fmaf(sA[r * TD + k], w, acc[r]);
        }
        if (half) {
#pragma unroll
            for (int r = 0; r < ROWS_T; r++) sAcc[r * H + h] = acc[r];
        }
        __syncthreads();
        if (!half) {
            const float bv = bt[h];
#pragma unroll
            for (int r = 0; r < ROWS_T; r++)
                tf[(i0 + r) * H + h] = acc[r] + sAcc[r * H + h] + bv;
        }
    } else if (b < NBLK_T + NBLK_D) {
        // ---- drug GEMM ----
        const int h = t & (H - 1), half = t >> 7, i0 = (b - NBLK_T) * ROWS_D;
        for (int idx = t; idx < ROWS_D * DD; idx += 256)
            sA[idx] = Ad[i0 * DD + idx];
        __syncthreads();
        float acc[ROWS_D];
#pragma unroll
        for (int r = 0; r < ROWS_D; r++) acc[r] = 0.0f;
        const int k0 = half * (DD / 2), k1 = k0 + (DD / 2);
#pragma unroll 4
        for (int k = k0; k < k1; k++) {
            const float w = Wd[k * H + h];
#pragma unroll
            for (int r = 0; r < ROWS_D; r++)
                acc[r] = fmaf(sA[r * DD + k], w, acc[r]);
        }
        if (half) {
#pragma unroll
            for (int r = 0; r < ROWS_D; r++) sAcc[r * H + h] = acc[r];
        }
        __syncthreads();
        if (!half) {
            const float bv = bd[h];
#pragma unroll
            for (int r = 0; r < ROWS_D; r++)
                df[(i0 + r) * H + h] = acc[r] + sAcc[r * H + h] + bv;
        }
    } else {
        // ---- per-residue distances + masked row min/max (dense write) ----
        const int i  = b - NBLK_T - NBLK_D;
        const int sr = seg_res[i];
        const float tx = tpos[3 * i], ty = tpos[3 * i + 1], tz = tpos[3 * i + 2];
        float vmin = INFINITY, vmax = -INFINITY;
        for (int j = t; j < NA; j += 256) {
            const float dx = tx - dpos[3 * j];
            const float dy = ty - dpos[3 * j + 1];
            const float dz = tz - dpos[3 * j + 2];
            const float d  = sqrtf(dx * dx + dy * dy + dz * dz);
            Dbuf[i * NA + j] = d;
            if (seg_atom[j] == sr) {
                vmin = fminf(vmin, d);
                vmax = fmaxf(vmax, d);
            }
        }
#pragma unroll
        for (int off = 32; off > 0; off >>= 1) {
            vmin = fminf(vmin, __shfl_down(vmin, off));
            vmax = fmaxf(vmax, __shfl_down(vmax, off));
        }
        const int wid = t >> 6, lane = t & 63;
        if (lane == 0) { sAcc[wid] = vmin; sAcc[4 + wid] = vmax; }
        __syncthreads();
        if (t == 0) {
            float mn = sAcc[0], mx = sAcc[4];
#pragma unroll
            for (int w = 1; w < 4; w++) {
                mn = fminf(mn, sAcc[w]);
                mx = fmaxf(mx, sAcc[4 + w]);
            }
            rowmin[i] = mn;
            rowmax[i] = mx;
        }
    }
}

// ---------------- segment reduce -> params[B] = {dmin, 1/denom} ---------
// 1 block, 512 threads, wave s handles segment s. No atomics.
__global__ __launch_bounds__(512) void segreduce_kernel(
    const float* __restrict__ rowmin, const float* __restrict__ rowmax,
    const int* __restrict__ seg_res, float2* __restrict__ params) {
    const int s    = threadIdx.x >> 6;  // 0..7
    const int lane = threadIdx.x & 63;
    float mn = INFINITY, mx = -INFINITY;
    for (int r = lane; r < NR; r += 64) {
        if (seg_res[r] == s) {
            mn = fminf(mn, rowmin[r]);
            mx = fmaxf(mx, rowmax[r]);
        }
    }
#pragma unroll
    for (int off = 32; off > 0; off >>= 1) {
        mn = fminf(mn, __shfl_down(mn, off));
        mx = fmaxf(mx, __shfl_down(mx, off));
    }
    if (lane == 0) {
        const float dmin = (mn < INFINITY)  ? mn : 0.0f;
        const float dmax = (mx > -INFINITY) ? mx : 1.0f;
        const float denom = (dmax > dmin) ? (dmax - dmin) : 1.0f;
        params[s] = make_float2(dmin, 1.0f / denom);
    }
}

// ---------------- fast tanh --------------------------------------------
__device__ __forceinline__ float fast_tanh(float x) {
    const float cx = fminf(fmaxf(x, -15.0f), 15.0f);
    const float e  = __expf(2.0f * cx);
    return 1.0f - __fdividef(2.0f, e + 1.0f);
}

// ---------------- the 524 MB writer -------------------------------------
// grid = (40, NR): blockIdx.y = residue i, so seg_res[i] / row bases are
// block-uniform scalars. Store layout IDENTICAL to round-4 (4 contiguous
// elems/thread, fully coalesced 1 KB/wave NT float4) — only the per-thread
// index arithmetic is removed.
__global__ __launch_bounds__(256) void final_kernel(
    const float* __restrict__ tf, const float* __restrict__ df,
    const float* __restrict__ Dbuf,
    const int* __restrict__ seg_res, const int* __restrict__ seg_atom,
    const float2* __restrict__ params, float* __restrict__ out) {
    const int i = blockIdx.y;
    const int e = (blockIdx.x * 256 + threadIdx.x) * 4;  // 0..40959 within row
    const int j = e >> 7;
    const int h = e & 127;

    f4 o = {0.0f, 0.0f, 0.0f, 0.0f};
    const int sr = seg_res[i];
    if (seg_atom[j] == sr) {
        const float2 pp = params[sr];
        const float  dn = (Dbuf[i * NA + j] - pp.x) * pp.y;
        const f4 tv = *(const f4*)(tf + i * H + h);
        const f4 dv = *(const f4*)(df + j * H + h);
        o.x = fast_tanh(tv.x - dv.x + dn);
        o.y = fast_tanh(tv.y - dv.y + dn);
        o.z = fast_tanh(tv.z - dv.z + dn);
        o.w = fast_tanh(tv.w - dv.w + dn);
    }
    __builtin_nontemporal_store(o, (f4*)(out + (long long)i * (NA * H) + e));
}

extern "C" void kernel_launch(void* const* d_in, const int* in_sizes, int n_in,
                              void* d_out, int out_size, void* d_ws, size_t ws_size,
                              hipStream_t stream) {
    const float* target_feature = (const float*)d_in[0];  // [NR, TD]
    const float* drug_feature   = (const float*)d_in[1];  // [NA, DD]
    const float* target_pos     = (const float*)d_in[2];  // [NR, 3]
    const float* drug_pos       = (const float*)d_in[3];  // [NA, 3]
    const float* Wt             = (const float*)d_in[4];  // [TD, H]
    const float* bt             = (const float*)d_in[5];  // [H]
    const float* Wd             = (const float*)d_in[6];  // [DD, H]
    const float* bd             = (const float*)d_in[7];  // [H]
    const int*   seg_res        = (const int*)d_in[8];    // [NR]
    const int*   seg_atom       = (const int*)d_in[9];    // [NA]
    float* out = (float*)d_out;

    // workspace (floats): tf | df | Dbuf | rowmin | rowmax | params
    float* ws     = (float*)d_ws;
    float* tf     = ws;                  // NR*H = 409,600
    float* df     = tf + NR * H;         // NA*H =  40,960
    float* Dbuf   = df + NA * H;         // NP   = 1,024,000
    float* rowmin = Dbuf + NP;           // NR
    float* rowmax = rowmin + NR;         // NR
    float2* params = (float2*)(rowmax + NR);  // B

    mega_kernel<<<NBLK_T + NBLK_D + NR, 256, 0, stream>>>(
        target_feature, Wt, bt, drug_feature, Wd, bd,
        target_pos, drug_pos, seg_res, seg_atom, tf, df, Dbuf, rowmin, rowmax);
    segreduce_kernel<<<1, 512, 0, stream>>>(rowmin, rowmax, seg_res, params);
    final_kernel<<<dim3(NA * H / (4 * 256), NR), 256, 0, stream>>>(
        tf, df, Dbuf, seg_res, seg_atom, params, out);
}